// Round 1
// baseline (204.135 us; speedup 1.0000x reference)
//
#include <hip/hip_runtime.h>

// YOLO v1 loss, B=16384, S=7, C=30. Memory-bound reduction: 192.7 MB read -> 1 float.
// Layout: pred[((b*S+i)*S+j)*30 + c]; i -> gi (x offset), j -> gj (y offset).

#define NS 7
#define NC 30

__global__ void zero_out_kernel(float* out) { out[0] = 0.0f; }

__global__ __launch_bounds__(256) void yolo_loss_kernel(
    const float* __restrict__ pred,
    const float* __restrict__ targ,
    float* __restrict__ out,
    int n_cells, float inv_B)
{
    const float STEP = 1.0f / 7.0f;
    const float L_COORD = 5.0f;
    const float L_NOOBJ = 0.5f;

    int cell = blockIdx.x * blockDim.x + threadIdx.x;
    float lsum = 0.0f;
    if (cell < n_cells) {
        int j = cell % NS;            // second spatial axis -> gj
        int i = (cell / NS) % NS;     // first spatial axis  -> gi
        float gi = (float)i;
        float gj = (float)j;

        // 30 floats = 15 aligned float2 per cell (120 B stride, 8 B aligned).
        const float2* p2 = (const float2*)pred + (size_t)cell * 15;
        const float2* t2 = (const float2*)targ + (size_t)cell * 15;
        float p[NC], t[NC];
        #pragma unroll
        for (int k = 0; k < 15; ++k) {
            float2 v = p2[k]; p[2 * k] = v.x; p[2 * k + 1] = v.y;
        }
        #pragma unroll
        for (int k = 0; k < 15; ++k) {
            float2 u = t2[k]; t[2 * k] = u.x; t[2 * k + 1] = u.y;
        }

        // _convert_box for target, pred box1 (ch 0:4), pred box2 (ch 5:9)
        float ta, tb, tc, td;
        {
            float cx = (t[0] + gi) * STEP;
            float cy = (t[1] + gj) * STEP;
            ta = fmaxf(cx - t[2] * 0.5f, 0.0f);
            tb = fmaxf(cy - t[3] * 0.5f, 0.0f);
            tc = fminf(cx + t[2] * 0.5f, 1.0f);
            td = fminf(cy + t[3] * 0.5f, 1.0f);
        }
        float q1, w1, e1, r1;
        {
            float cx = (p[0] + gi) * STEP;
            float cy = (p[1] + gj) * STEP;
            q1 = fmaxf(cx - p[2] * 0.5f, 0.0f);
            w1 = fmaxf(cy - p[3] * 0.5f, 0.0f);
            e1 = fminf(cx + p[2] * 0.5f, 1.0f);
            r1 = fminf(cy + p[3] * 0.5f, 1.0f);
        }
        float q2, w2, e2, r2;
        {
            float cx = (p[5] + gi) * STEP;
            float cy = (p[6] + gj) * STEP;
            q2 = fmaxf(cx - p[7] * 0.5f, 0.0f);
            w2 = fmaxf(cy - p[8] * 0.5f, 0.0f);
            e2 = fminf(cx + p[7] * 0.5f, 1.0f);
            r2 = fminf(cy + p[8] * 0.5f, 1.0f);
        }

        float tarea = (td - tb) * (tc - ta);
        // _iou(tbox, pbox): inter NOT clamped; iou = inter>0 ? inter/(union+1e-5) : 0
        float iou1, iou2;
        {
            float minx = fmaxf(ta, q1), miny = fmaxf(tb, w1);
            float maxx = fminf(tc, e1), maxy = fminf(td, r1);
            float inter = (maxy - miny) * (maxx - minx);
            float uni = (e1 - q1) * (r1 - w1) + tarea - inter;
            iou1 = (inter > 0.0f) ? inter / (uni + 1e-5f) : 0.0f;
        }
        {
            float minx = fmaxf(ta, q2), miny = fmaxf(tb, w2);
            float maxx = fminf(tc, e2), maxy = fminf(td, r2);
            float inter = (maxy - miny) * (maxx - minx);
            float uni = (e2 - q2) * (r2 - w2) + tarea - inter;
            iou2 = (inter > 0.0f) ? inter / (uni + 1e-5f) : 0.0f;
        }

        bool sel2 = (iou1 <= iou2);
        float conf_t = sel2 ? iou2 : iou1;
        float px = sel2 ? p[5] : p[0];
        float py = sel2 ? p[6] : p[1];
        float pw = sel2 ? p[7] : p[2];
        float ph = sel2 ? p[8] : p[3];
        float pconf = sel2 ? p[9] : p[4];

        float obj = (t[4] > 0.0f) ? 1.0f : 0.0f;
        float noobj = (t[4] == 0.0f) ? 1.0f : 0.0f;

        float dx = px - t[0], dy = py - t[1];
        float dw = pw - t[2], dh = ph - t[3];
        float coord = dx * dx + dy * dy + dw * dw + dh * dh;

        float dc = pconf - conf_t;
        float obj_loss = dc * dc;

        float cls = 0.0f;
        #pragma unroll
        for (int k = 10; k < NC; ++k) {
            float d = p[k] - t[k];
            cls += d * d;
        }

        float d4 = p[4] - t[4];
        float d9 = p[9] - t[9];
        float noobj_loss = d4 * d4 + d9 * d9;

        lsum = obj * (obj_loss + L_COORD * coord + cls) + L_NOOBJ * noobj * noobj_loss;
    }

    // wave(64) shuffle reduce
    #pragma unroll
    for (int off = 32; off > 0; off >>= 1)
        lsum += __shfl_down(lsum, off, 64);

    __shared__ float wsum[4];
    int lane = threadIdx.x & 63;
    int wid = threadIdx.x >> 6;
    if (lane == 0) wsum[wid] = lsum;
    __syncthreads();
    if (threadIdx.x == 0) {
        float s = (wsum[0] + wsum[1]) + (wsum[2] + wsum[3]);
        atomicAdd(out, s * inv_B);
    }
}

extern "C" void kernel_launch(void* const* d_in, const int* in_sizes, int n_in,
                              void* d_out, int out_size, void* d_ws, size_t ws_size,
                              hipStream_t stream) {
    const float* pred = (const float*)d_in[0];
    const float* targ = (const float*)d_in[1];
    float* out = (float*)d_out;

    const int B = 16384;
    const int n_cells = B * NS * NS;  // 802816
    const float inv_B = 1.0f / (float)B;

    zero_out_kernel<<<1, 1, 0, stream>>>(out);

    const int block = 256;
    const int grid = (n_cells + block - 1) / block;  // 3136
    yolo_loss_kernel<<<grid, block, 0, stream>>>(pred, targ, out, n_cells, inv_B);
}